// Round 15
// baseline (224.994 us; speedup 1.0000x reference)
//
#include <hip/hip_runtime.h>
#include <hip/hip_bf16.h>
#include <math.h>

// Problem constants (fixed shapes from setup_inputs)
#define B_   16
#define F_   2048
#define N_   64
#define K_   1024   // F/2
#define YP   2040   // padded LDS row stride (ushorts); 16B-aligned rows

typedef short bf16x8 __attribute__((ext_vector_type(8)));  // 8 bf16 = 4 VGPR
typedef float v4f    __attribute__((ext_vector_type(4)));  // MFMA C/D frag

__device__ __forceinline__ float wave_sum(float v) {
#pragma unroll
  for (int off = 32; off > 0; off >>= 1) v += __shfl_down(v, off, 64);
  return v;
}
__device__ __forceinline__ float wave_max(float v) {
#pragma unroll
  for (int off = 32; off > 0; off >>= 1) v = fmaxf(v, __shfl_down(v, off, 64));
  return v;
}

// fp32 -> bf16 bits, round-to-nearest-even (finite inputs only)
__device__ __forceinline__ unsigned f2bf(float x) {
  const unsigned u = __float_as_uint(x);
  return (u + 0x7FFFu + ((u >> 16) & 1u)) >> 16;
}
__device__ __forceinline__ float bf2f(unsigned us) {
  return __uint_as_float(us << 16);
}
// 16-bit total-order inverse: ord -> bf16 bits
__device__ __forceinline__ unsigned ord2u16(unsigned T) {
  return (T & 0x8000u) ? (T ^ 0x8000u) : (T ^ 0xFFFFu);
}
// packed pair of ord16 keys from a dword of 2 bf16 values
__device__ __forceinline__ unsigned ordpair(unsigned wd) {
  return wd ^ (0x80008000u | (((wd & 0x80008000u) >> 15) * 0x7FFFu));
}

// K0 (round-8, verified): wide grid, fb-MAJOR P layout, atomic-free.
__global__ __launch_bounds__(256) void stats_kernel(
    const float* __restrict__ X, const float* __restrict__ M,
    float* __restrict__ P) {
  __shared__ float red[4][N_][4];   // [fi][n][word], 4 KB
  const int tid = threadIdx.x;
  const int b = blockIdx.x >> 6;
  const int fb = blockIdx.x & 63;
  const int f0 = fb * 32;
  const int fi = tid >> 6, n = tid & 63;
  float sx = 0.f, sxx = 0.f, sm = 0.f, smm = 0.f;
#pragma unroll
  for (int j = 0; j < 8; ++j) {
    const int f = f0 + fi + 4 * j;
    const size_t gi = ((size_t)b * F_ + f) * N_ + n;
    const float x = X[gi];
    const float m = M[gi];
    sx += x; sxx += x * x; sm += m; smm += m * m;
  }
  red[fi][n][0] = sx; red[fi][n][1] = sxx;
  red[fi][n][2] = sm; red[fi][n][3] = smm;
  __syncthreads();
  const int wn = tid & 63, word = tid >> 6;
  const float s = red[0][wn][word] + red[1][wn][word] +
                  red[2][wn][word] + red[3][wn][word];
  P[(size_t)fb * 4096 + b * 256 + wn * 4 + word] = s;
}

// K0b (round-8, verified): hierarchical reduce P(1MB) -> S(16KB).
__global__ __launch_bounds__(256) void reduce_kernel(
    const float* __restrict__ P, float* __restrict__ S) {
  const int i = blockIdx.x * 256 + threadIdx.x;   // 0..4095 = b*256+n*4+word
  float s0 = 0.f, s1 = 0.f, s2 = 0.f, s3 = 0.f;
#pragma unroll
  for (int fb = 0; fb < 64; fb += 4) {
    s0 += P[(size_t)fb * 4096 + i];
    s1 += P[(size_t)(fb + 1) * 4096 + i];
    s2 += P[(size_t)(fb + 2) * 4096 + i];
    s3 += P[(size_t)(fb + 3) * 4096 + i];
  }
  S[i] = (s0 + s1) + (s2 + s3);
}

// K1 (round-8, verified): one float4 S-read; packed-MFMA-order bf16 out.
__global__ __launch_bounds__(256) void normbf_kernel(
    const float* __restrict__ X, const float* __restrict__ M,
    const float* __restrict__ S,
    short* __restrict__ Xb16, short* __restrict__ Mb16) {
  const int tid = threadIdx.x;
  const int b = blockIdx.x >> 6;
  const int f0 = (blockIdx.x & 63) * 32;
  const int n = tid & 63;
  const float4 s4 = ((const float4*)S)[b * 64 + n];  // sx,sxx,sm,smm
  const float sx = s4.x, sxx = s4.y, sm = s4.z, smm = s4.w;
  const float mux = sx * (1.f / F_), mum = sm * (1.f / F_);
  const float rx = 1.f / (sqrtf(fmaxf(sxx - (float)F_ * mux * mux, 0.f)) + 1e-10f);
  const float rm = 1.f / (sqrtf(fmaxf(smm - (float)F_ * mum * mum, 0.f)) + 1e-10f);
  const int s_ = n >> 5, q_ = (n >> 3) & 3, j_ = n & 7;
#pragma unroll
  for (int jj = 0; jj < 8; ++jj) {
    const int f = f0 + (tid >> 6) + 4 * jj;
    const size_t gi = ((size_t)b * F_ + f) * N_ + n;
    const int t16 = f >> 4, nl = f & 15;
    const size_t pi = (((size_t)b * 128 + t16) * 2 + s_) * 512 +
                      (q_ * 16 + nl) * 8 + j_;
    Xb16[pi] = (short)f2bf((X[gi] - mux) * rx);
    Mb16[pi] = (short)f2bf((M[gi] - mum) * rm);
  }
}

// K2 (round-15): 32-ROW BLOCKS (1024 thr, 16 waves) — each block reads the
// 512KB B-panel ONCE for 32 output rows instead of 16, halving total L2
// B-traffic (2048x512KB=1GB -> 0.5GB; ~30us L2-BW floor -> ~15).
// LDS = 32xYP yxu (130,560) + 32 hists (32,768) = 163,328 <= 160KB ->
// 1 block/CU = 16 waves/CU (same wave count as round-14's 2x512).
// Per-wave GEMM + dual-row selection code byte-identical to round-14
// (verified); only the block->(row,col) mapping changed:
// rgrp=w>>3 picks A-chunk (16-row half), cgrp=w&7 picks 256-col slice.
__global__ __launch_bounds__(1024)
__attribute__((amdgpu_waves_per_eu(4, 4)))
void rows_kernel(
    const short* __restrict__ Xb16, const short* __restrict__ Mb16,
    float* __restrict__ C) {
  __shared__ unsigned short yxu[32 * YP];   // 130,560 B
  __shared__ unsigned histS[32 * 256];      // 32,768 B: 2 hists per wave

  const int tid = threadIdx.x;
  const int w = tid >> 6, lane = tid & 63;
  const int nl = lane & 15, q = lane >> 4;
  const int b = blockIdx.x >> 6;            // 64 row-blocks per batch
  const int f0 = (blockIdx.x & 63) * 32;
  const int rgrp = w >> 3;                  // 0/1: which 16-row half
  const int cgrp = w & 7;                   // 256-col slice
  const int g0 = 256 * cgrp;

  const short* __restrict__ Xb = Xb16 + (size_t)b * F_ * N_;
  const short* __restrict__ Mb = Mb16 + (size_t)b * F_ * N_;

  // A-frags: packed chunk t16 = f0>>4 + rgrp; s=0/1 halves adjacent
  const int t16A = (f0 >> 4) + rgrp;
  const short* Axp = Xb + (size_t)t16A * 1024 + lane * 8;
  const short* Amp = Mb + (size_t)t16A * 1024 + lane * 8;
  const bf16x8 ax0 = *(const bf16x8*)(Axp);
  const bf16x8 ax1 = *(const bf16x8*)(Axp + 512);
  const bf16x8 am0 = *(const bf16x8*)(Amp);
  const bf16x8 am1 = *(const bf16x8*)(Amp + 512);

  v4f acc[16];
#pragma unroll
  for (int t = 0; t < 16; ++t) acc[t] = (v4f)(0.f);

#pragma unroll
  for (int t = 0; t < 16; ++t) {
    // B chunk t16 = 16*cgrp + t
    const short* Bmp = Mb + (size_t)(16 * cgrp + t) * 1024 + lane * 8;
    const short* Bxp = Xb + (size_t)(16 * cgrp + t) * 1024 + lane * 8;
    const bf16x8 bm0 = *(const bf16x8*)(Bmp);
    const bf16x8 bm1 = *(const bf16x8*)(Bmp + 512);
    const bf16x8 bx0 = *(const bf16x8*)(Bxp);
    const bf16x8 bx1 = *(const bf16x8*)(Bxp + 512);
    acc[t] = __builtin_amdgcn_mfma_f32_16x16x32_bf16(ax0, bm0, acc[t], 0, 0, 0);
    acc[t] = __builtin_amdgcn_mfma_f32_16x16x32_bf16(ax1, bm1, acc[t], 0, 0, 0);
    acc[t] = __builtin_amdgcn_mfma_f32_16x16x32_bf16(am0, bx0, acc[t], 0, 0, 0);
    acc[t] = __builtin_amdgcn_mfma_f32_16x16x32_bf16(am1, bx1, acc[t], 0, 0, 0);
  }

  // C-frag (col=lane&15, row=q*4+r, verified m89/m91) -> LDS bf16 keys
#pragma unroll
  for (int t = 0; t < 16; ++t) {
    const int col = g0 + 16 * t + nl;
#pragma unroll
    for (int r = 0; r < 4; ++r)
      yxu[(16 * rgrp + 4 * q + r) * YP + col] = (unsigned short)f2bf(acc[t][r]);
  }
  __syncthreads();

  // ---- dual-row selection: rows 2w (suffix 0) and 2w+1 (suffix 1) ----
  unsigned* wh0 = &histS[w << 9];
  unsigned* wh1 = wh0 + 256;
  const int frow0 = f0 + 2 * w, frow1 = frow0 + 1;
  const uint4* rp0 = (const uint4*)(yxu + (2 * w) * YP);
  const uint4* rp1 = (const uint4*)(yxu + (2 * w + 1) * YP);

  // pk load + ordpair + min/max, both rows interleaved
  unsigned pk0[16], pk1[16];
  unsigned kmin0 = 0xFFFFFFFFu, kmax0 = 0u, kmin1 = 0xFFFFFFFFu, kmax1 = 0u;
#pragma unroll
  for (int j = 0; j < 4; ++j) {
    const uint4 t0 = rp0[lane + 64 * j];
    const uint4 t1 = rp1[lane + 64 * j];
    const unsigned w0[4] = {t0.x, t0.y, t0.z, t0.w};
    const unsigned w1[4] = {t1.x, t1.y, t1.z, t1.w};
#pragma unroll
    for (int c = 0; c < 4; ++c) {
      const unsigned o0 = ordpair(w0[c]), o1 = ordpair(w1[c]);
      pk0[4 * j + c] = o0; pk1[4 * j + c] = o1;
      kmin0 = min(kmin0, min(o0 & 0xFFFFu, o0 >> 16));
      kmax0 = max(kmax0, max(o0 & 0xFFFFu, o0 >> 16));
      kmin1 = min(kmin1, min(o1 & 0xFFFFu, o1 >> 16));
      kmax1 = max(kmax1, max(o1 & 0xFFFFu, o1 >> 16));
    }
  }
#pragma unroll
  for (int off = 32; off > 0; off >>= 1) {
    kmin0 = min(kmin0, (unsigned)__shfl_down((int)kmin0, off, 64));
    kmin1 = min(kmin1, (unsigned)__shfl_down((int)kmin1, off, 64));
    kmax0 = max(kmax0, (unsigned)__shfl_down((int)kmax0, off, 64));
    kmax1 = max(kmax1, (unsigned)__shfl_down((int)kmax1, off, 64));
  }
  kmin0 = (unsigned)__shfl((int)kmin0, 0, 64);
  kmax0 = (unsigned)__shfl((int)kmax0, 0, 64);
  kmin1 = (unsigned)__shfl((int)kmin1, 0, 64);
  kmax1 = (unsigned)__shfl((int)kmax1, 0, 64);

  // radix state per row; <=2 passes, shared barriers, own histograms
  unsigned lo0 = kmin0, R0 = kmax0 - kmin0, krem0 = K_, T0 = 0, tn0 = 0;
  unsigned lo1 = kmin1, R1 = kmax1 - kmin1, krem1 = K_, T1 = 0, tn1 = 0;
  bool done0 = false, done1 = false;
  if (R0 == 0) { T0 = lo0; tn0 = krem0; done0 = true; }
  if (R1 == 0) { T1 = lo1; tn1 = krem1; done1 = true; }

#pragma unroll 1
  for (int pass = 0; pass < 2 && !(done0 && done1); ++pass) {
    int sh0 = 0, sh1 = 0;
    if (!done0) { const int p = 31 - __builtin_clz(R0); sh0 = (p > 7) ? (p - 7) : 0; }
    if (!done1) { const int p = 31 - __builtin_clz(R1); sh1 = (p > 7) ? (p - 7) : 0; }
#pragma unroll
    for (int i = 0; i < 4; ++i) { wh0[lane + 64 * i] = 0u; wh1[lane + 64 * i] = 0u; }
    __builtin_amdgcn_wave_barrier();
    if (!done0) {
#pragma unroll
      for (int c = 0; c < 16; ++c) {
        const unsigned o = pk0[c];
        const unsigned d0 = (o & 0xFFFFu) - lo0, d1 = (o >> 16) - lo0;
        if (d0 <= R0) atomicAdd(&wh0[d0 >> sh0], 1u);
        if (d1 <= R0) atomicAdd(&wh0[d1 >> sh0], 1u);
      }
    }
    if (!done1) {
#pragma unroll
      for (int c = 0; c < 16; ++c) {
        const unsigned o = pk1[c];
        const unsigned d0 = (o & 0xFFFFu) - lo1, d1 = (o >> 16) - lo1;
        if (d0 <= R1) atomicAdd(&wh1[d0 >> sh1], 1u);
        if (d1 <= R1) atomicAdd(&wh1[d1 >> sh1], 1u);
      }
    }
    __builtin_amdgcn_wave_barrier();
    // scans: two interleaved chains (wave-uniform predicates)
    unsigned h0[4], h1[4];
#pragma unroll
    for (int i = 0; i < 4; ++i) { h0[i] = wh0[4 * lane + i]; h1[i] = wh1[4 * lane + i]; }
    unsigned a3 = h0[3], a2 = h0[2] + a3, a1 = h0[1] + a2, a0 = h0[0] + a1;
    unsigned b3 = h1[3], b2 = h1[2] + b3, b1 = h1[1] + b2, b0 = h1[0] + b1;
    unsigned tot0 = a0, tot1 = b0;
#pragma unroll
    for (int off = 1; off < 64; off <<= 1) {
      const unsigned v0 = __shfl_down(tot0, off, 64);
      const unsigned v1 = __shfl_down(tot1, off, 64);
      if (lane + off < 64) { tot0 += v0; tot1 += v1; }
    }
    if (!done0) {
      const unsigned above = tot0 - a0;
      const unsigned S4[4] = {above + a0, above + a1, above + a2, above + a3};
      unsigned packed = 0; bool found = false;
#pragma unroll
      for (int i = 0; i < 4; ++i) {
        const unsigned Sip1 = S4[i] - h0[i];
        if (S4[i] >= krem0 && Sip1 < krem0) {
          packed = ((unsigned)(4 * lane + i) << 16) | Sip1; found = true;
        }
      }
      const unsigned long long bm = __ballot(found);
      const int winner = __ffsll(bm) - 1;
      packed = (unsigned)__shfl((int)packed, winner, 64);
      const unsigned D = packed >> 16;
      krem0 -= (packed & 0xFFFFu);
      if (sh0 == 0) { T0 = lo0 + D; tn0 = krem0; done0 = true; }
      else { lo0 += (D << sh0); R0 = (1u << sh0) - 1u; }
    }
    if (!done1) {
      const unsigned above = tot1 - b0;
      const unsigned S4[4] = {above + b0, above + b1, above + b2, above + b3};
      unsigned packed = 0; bool found = false;
#pragma unroll
      for (int i = 0; i < 4; ++i) {
        const unsigned Sip1 = S4[i] - h1[i];
        if (S4[i] >= krem1 && Sip1 < krem1) {
          packed = ((unsigned)(4 * lane + i) << 16) | Sip1; found = true;
        }
      }
      const unsigned long long bm = __ballot(found);
      const int winner = __ffsll(bm) - 1;
      packed = (unsigned)__shfl((int)packed, winner, 64);
      const unsigned D = packed >> 16;
      krem1 -= (packed & 0xFFFFu);
      if (sh1 == 0) { T1 = lo1 + D; tn1 = krem1; done1 = true; }
      else { lo1 += (D << sh1); R1 = (1u << sh1) - 1u; }
    }
  }

  // final pass, both rows interleaved
  float vs0 = 0.f, ws0 = 0.f, vs1 = 0.f, ws1 = 0.f;
  unsigned cnt0[4], cnt1[4];
#pragma unroll
  for (int j = 0; j < 4; ++j) {
    cnt0[j] = 0; cnt1[j] = 0;
#pragma unroll
    for (int c = 0; c < 4; ++c) {
      const unsigned o0 = pk0[4 * j + c], o1 = pk1[4 * j + c];
      const unsigned z0[2] = {o0 & 0xFFFFu, o0 >> 16};
      const unsigned z1[2] = {o1 & 0xFFFFu, o1 >> 16};
#pragma unroll
      for (int i = 0; i < 2; ++i) {
        const int g = 512 * j + 8 * lane + 2 * c + i;
        if (z0[i] > T0) {
          const float pv = __expf(bf2f(ord2u16(z0[i])));
          vs0 += pv; ws0 += pv * fabsf((float)(g - frow0));
        } else if (z0[i] == T0) cnt0[j]++;
        if (z1[i] > T1) {
          const float pv = __expf(bf2f(ord2u16(z1[i])));
          vs1 += pv; ws1 += pv * fabsf((float)(g - frow1));
        } else if (z1[i] == T1) cnt1[j]++;
      }
    }
  }
  const float ptie0 = __expf(bf2f(ord2u16(T0)));
  const float ptie1 = __expf(bf2f(ord2u16(T1)));

  // tie scans: 4 packed prefix chains interleaved
  unsigned pA0 = cnt0[0] | (cnt0[1] << 16), pB0 = cnt0[2] | (cnt0[3] << 16);
  unsigned pA1 = cnt1[0] | (cnt1[1] << 16), pB1 = cnt1[2] | (cnt1[3] << 16);
  unsigned iA0 = pA0, iB0 = pB0, iA1 = pA1, iB1 = pB1;
#pragma unroll
  for (int off = 1; off < 64; off <<= 1) {
    const unsigned vA0 = __shfl_up(iA0, off, 64);
    const unsigned vB0 = __shfl_up(iB0, off, 64);
    const unsigned vA1 = __shfl_up(iA1, off, 64);
    const unsigned vB1 = __shfl_up(iB1, off, 64);
    if (lane >= off) { iA0 += vA0; iB0 += vB0; iA1 += vA1; iB1 += vB1; }
  }
  const unsigned eA0 = iA0 - pA0, eB0 = iB0 - pB0;
  const unsigned eA1 = iA1 - pA1, eB1 = iB1 - pB1;
  const unsigned tA0 = (unsigned)__shfl((int)iA0, 63, 64);
  const unsigned tB0 = (unsigned)__shfl((int)iB0, 63, 64);
  const unsigned tA1 = (unsigned)__shfl((int)iA1, 63, 64);
  const unsigned tB1 = (unsigned)__shfl((int)iB1, 63, 64);
  unsigned G0[4], G1[4];
  G0[0] = 0; G0[1] = tA0 & 0xFFFFu; G0[2] = G0[1] + (tA0 >> 16);
  G0[3] = G0[2] + (tB0 & 0xFFFFu);
  G1[0] = 0; G1[1] = tA1 & 0xFFFFu; G1[2] = G1[1] + (tA1 >> 16);
  G1[3] = G1[2] + (tB1 & 0xFFFFu);
#pragma unroll
  for (int j = 0; j < 4; ++j) {
    if (cnt0[j]) {
      const unsigned off = (j < 2) ? ((eA0 >> (16 * j)) & 0xFFFFu)
                                   : ((eB0 >> (16 * (j - 2))) & 0xFFFFu);
      unsigned cc = 0;
#pragma unroll
      for (int c = 0; c < 4; ++c) {
        const unsigned o = pk0[4 * j + c];
        const unsigned z[2] = {o & 0xFFFFu, o >> 16};
#pragma unroll
        for (int i = 0; i < 2; ++i) {
          if (z[i] == T0) {
            if (G0[j] + off + cc < tn0) {
              const int g = 512 * j + 8 * lane + 2 * c + i;
              vs0 += ptie0; ws0 += ptie0 * fabsf((float)(g - frow0));
            }
            cc++;
          }
        }
      }
    }
    if (cnt1[j]) {
      const unsigned off = (j < 2) ? ((eA1 >> (16 * j)) & 0xFFFFu)
                                   : ((eB1 >> (16 * (j - 2))) & 0xFFFFu);
      unsigned cc = 0;
#pragma unroll
      for (int c = 0; c < 4; ++c) {
        const unsigned o = pk1[4 * j + c];
        const unsigned z[2] = {o & 0xFFFFu, o >> 16};
#pragma unroll
        for (int i = 0; i < 2; ++i) {
          if (z[i] == T1) {
            if (G1[j] + off + cc < tn1) {
              const int g = 512 * j + 8 * lane + 2 * c + i;
              vs1 += ptie1; ws1 += ptie1 * fabsf((float)(g - frow1));
            }
            cc++;
          }
        }
      }
    }
  }

  // 4 interleaved wave reductions
#pragma unroll
  for (int off = 32; off > 0; off >>= 1) {
    vs0 += __shfl_down(vs0, off, 64);
    ws0 += __shfl_down(ws0, off, 64);
    vs1 += __shfl_down(vs1, off, 64);
    ws1 += __shfl_down(ws1, off, 64);
  }
  if (lane == 0) {
    C[(size_t)b * F_ + frow0] = (ws0 / vs0) * (1.f / (float)K_);
    C[(size_t)b * F_ + frow1] = (ws1 / vs1) * (1.f / (float)K_);
  }
}

// K3: cmin = min(C); out = mean(exp(-C + cmin - 1e-6)) (unchanged).
__global__ __launch_bounds__(1024) void final_kernel(
    const float* __restrict__ C, unsigned* __restrict__ out) {
  __shared__ float red[16];
  const int tid = threadIdx.x;
  const int wave = tid >> 6, lane = tid & 63;
  float v[32];
  float mn = 3.4e38f;
#pragma unroll
  for (int i = 0; i < 32; ++i) {
    v[i] = C[tid + 1024 * i];
    mn = fminf(mn, v[i]);
  }
  mn = -wave_max(-mn);
  if (lane == 0) red[wave] = mn;
  __syncthreads();
  float cmin = red[0];
  for (int w = 1; w < 16; ++w) cmin = fminf(cmin, red[w]);
  __syncthreads();
  float s = 0.f;
#pragma unroll
  for (int i = 0; i < 32; ++i) s += expf(cmin - v[i] - 1e-6f);
  s = wave_sum(s);
  if (lane == 0) red[wave] = s;
  __syncthreads();
  if (tid == 0) {
    float tot = 0.f;
    for (int w = 0; w < 16; ++w) tot += red[w];
    const float res = tot * (1.f / 32768.f);
    const __hip_bfloat16 hb = __float2bfloat16(res);
    const unsigned short u = *(const unsigned short*)&hb;
    out[0] = ((unsigned)u << 16) | (unsigned)u;
  }
}

extern "C" void kernel_launch(void* const* d_in, const int* in_sizes, int n_in,
                              void* d_out, int out_size, void* d_ws, size_t ws_size,
                              hipStream_t stream) {
  const float* X = (const float*)d_in[0];
  const float* M = (const float*)d_in[1];
  short* Xb16 = (short*)d_ws;                          // 4 MB (packed frags)
  short* Mb16 = Xb16 + (size_t)B_ * F_ * N_;           // 4 MB
  float* C = (float*)(Mb16 + (size_t)B_ * F_ * N_);    // 128 KB
  float* P = C + (size_t)B_ * F_;                      // 1 MB fb-major partials
  float* S = P + (size_t)64 * 4096;                    // 16 KB reduced stats

  stats_kernel<<<dim3(B_ * 64), dim3(256), 0, stream>>>(X, M, P);
  reduce_kernel<<<dim3(16), dim3(256), 0, stream>>>(P, S);
  normbf_kernel<<<dim3(B_ * 64), dim3(256), 0, stream>>>(X, M, S, Xb16, Mb16);
  rows_kernel<<<dim3(B_ * (F_ / 32)), dim3(1024), 0, stream>>>(Xb16, Mb16, C);
  final_kernel<<<dim3(1), dim3(1024), 0, stream>>>(C, (unsigned*)d_out);
}

// Round 17
// 194.469 us; speedup vs baseline: 1.1570x; 1.1570x over previous
//
#include <hip/hip_runtime.h>
#include <hip/hip_bf16.h>
#include <math.h>

// Problem constants (fixed shapes from setup_inputs)
#define B_   16
#define F_   2048
#define N_   64
#define K_   1024   // F/2
#define YP   2040   // padded LDS row stride (ushorts); 16B-aligned rows

typedef short bf16x8 __attribute__((ext_vector_type(8)));  // 8 bf16 = 4 VGPR
typedef float v4f    __attribute__((ext_vector_type(4)));  // MFMA C/D frag

__device__ __forceinline__ float wave_sum(float v) {
#pragma unroll
  for (int off = 32; off > 0; off >>= 1) v += __shfl_down(v, off, 64);
  return v;
}
__device__ __forceinline__ float wave_max(float v) {
#pragma unroll
  for (int off = 32; off > 0; off >>= 1) v = fmaxf(v, __shfl_down(v, off, 64));
  return v;
}

// fp32 -> bf16 bits, round-to-nearest-even (finite inputs only)
__device__ __forceinline__ unsigned f2bf(float x) {
  const unsigned u = __float_as_uint(x);
  return (u + 0x7FFFu + ((u >> 16) & 1u)) >> 16;
}
__device__ __forceinline__ float bf2f(unsigned us) {
  return __uint_as_float(us << 16);
}
// 16-bit total-order inverse: ord -> bf16 bits
__device__ __forceinline__ unsigned ord2u16(unsigned T) {
  return (T & 0x8000u) ? (T ^ 0x8000u) : (T ^ 0xFFFFu);
}
// packed pair of ord16 keys from a dword of 2 bf16 values
__device__ __forceinline__ unsigned ordpair(unsigned wd) {
  return wd ^ (0x80008000u | (((wd & 0x80008000u) >> 15) * 0x7FFFu));
}

// K0 (round-8, verified): wide grid, fb-MAJOR P layout, atomic-free.
__global__ __launch_bounds__(256) void stats_kernel(
    const float* __restrict__ X, const float* __restrict__ M,
    float* __restrict__ P) {
  __shared__ float red[4][N_][4];   // [fi][n][word], 4 KB
  const int tid = threadIdx.x;
  const int b = blockIdx.x >> 6;
  const int fb = blockIdx.x & 63;
  const int f0 = fb * 32;
  const int fi = tid >> 6, n = tid & 63;
  float sx = 0.f, sxx = 0.f, sm = 0.f, smm = 0.f;
#pragma unroll
  for (int j = 0; j < 8; ++j) {
    const int f = f0 + fi + 4 * j;
    const size_t gi = ((size_t)b * F_ + f) * N_ + n;
    const float x = X[gi];
    const float m = M[gi];
    sx += x; sxx += x * x; sm += m; smm += m * m;
  }
  red[fi][n][0] = sx; red[fi][n][1] = sxx;
  red[fi][n][2] = sm; red[fi][n][3] = smm;
  __syncthreads();
  const int wn = tid & 63, word = tid >> 6;
  const float s = red[0][wn][word] + red[1][wn][word] +
                  red[2][wn][word] + red[3][wn][word];
  P[(size_t)fb * 4096 + b * 256 + wn * 4 + word] = s;
}

// K0b (round-8, verified): hierarchical reduce P(1MB) -> S(16KB).
__global__ __launch_bounds__(256) void reduce_kernel(
    const float* __restrict__ P, float* __restrict__ S) {
  const int i = blockIdx.x * 256 + threadIdx.x;   // 0..4095 = b*256+n*4+word
  float s0 = 0.f, s1 = 0.f, s2 = 0.f, s3 = 0.f;
#pragma unroll
  for (int fb = 0; fb < 64; fb += 4) {
    s0 += P[(size_t)fb * 4096 + i];
    s1 += P[(size_t)(fb + 1) * 4096 + i];
    s2 += P[(size_t)(fb + 2) * 4096 + i];
    s3 += P[(size_t)(fb + 3) * 4096 + i];
  }
  S[i] = (s0 + s1) + (s2 + s3);
}

// K1 (round-16): LDS-STAGED normbf. The old version stored packed bf16 as
// 16 scalar-short stores x 8 discontiguous 16B segments per wave (TA
// segmentation, round-5 disease). New mapping: thread = (t16l, nl, s, q)
// owns f fixed and 8 CONSECUTIVE n: reads 2x float4 contiguous (256
// threads cover one contiguous 8KB run), per-n (mu,r) precomputed once
// into LDS, outputs packed in-register to uint4, staged via an 8KB LDS
// mirror of the block's 4 contiguous output chunks, copied out as
// fully-coalesced 16B stores. Output bytes identical to round-8 normbf.
__global__ __launch_bounds__(256) void normbf_kernel(
    const float* __restrict__ X, const float* __restrict__ M,
    const float* __restrict__ S,
    short* __restrict__ Xb16, short* __restrict__ Mb16) {
  __shared__ float4 Pl[64];               // (mux, rx, mum, rm) per n, 1 KB
  __shared__ unsigned short Xs[2048];     // 4 KB packed X (4 chunks)
  __shared__ unsigned short Ms[2048];     // 4 KB packed M
  const int tid = threadIdx.x;
  const int b = blockIdx.x >> 6;
  const int f0 = (blockIdx.x & 63) * 32;
  const int T = f0 >> 4;                  // first t16 chunk of this block
  if (tid < 64) {
    const float4 s4 = ((const float4*)S)[b * 64 + tid];  // sx,sxx,sm,smm
    const float mux = s4.x * (1.f / F_);
    const float mum = s4.z * (1.f / F_);
    const float rx =
        1.f / (sqrtf(fmaxf(s4.y - (float)F_ * mux * mux, 0.f)) + 1e-10f);
    const float rm =
        1.f / (sqrtf(fmaxf(s4.w - (float)F_ * mum * mum, 0.f)) + 1e-10f);
    Pl[tid] = make_float4(mux, rx, mum, rm);
  }
  __syncthreads();
  const int t16l = tid >> 7, r = tid & 127;
  const int nl = r >> 3, sq = r & 7;      // sq = s_*4 + q_
  const int f = (T + t16l) * 16 + nl;
  const int n0 = 8 * sq;                  // = 32*s_ + 8*q_
  const size_t gi = ((size_t)b * F_ + f) * N_ + n0;
  const float4 xa = *(const float4*)(X + gi);
  const float4 xb = *(const float4*)(X + gi + 4);
  const float4 ma = *(const float4*)(M + gi);
  const float4 mb = *(const float4*)(M + gi + 4);
  const float xs8[8] = {xa.x, xa.y, xa.z, xa.w, xb.x, xb.y, xb.z, xb.w};
  const float ms8[8] = {ma.x, ma.y, ma.z, ma.w, mb.x, mb.y, mb.z, mb.w};
  unsigned xv[8], mv[8];
#pragma unroll
  for (int j = 0; j < 8; ++j) {
    const float4 p = Pl[n0 + j];
    xv[j] = f2bf((xs8[j] - p.x) * p.y);
    mv[j] = f2bf((ms8[j] - p.z) * p.w);
  }
  const int s_ = sq >> 2, q_ = sq & 3;
  const int loff = (t16l * 2 + s_) * 512 + (q_ * 16 + nl) * 8;
  uint4 px, pm;
  px.x = xv[0] | (xv[1] << 16); px.y = xv[2] | (xv[3] << 16);
  px.z = xv[4] | (xv[5] << 16); px.w = xv[6] | (xv[7] << 16);
  pm.x = mv[0] | (mv[1] << 16); pm.y = mv[2] | (mv[3] << 16);
  pm.z = mv[4] | (mv[5] << 16); pm.w = mv[6] | (mv[7] << 16);
  *(uint4*)(&Xs[loff]) = px;
  *(uint4*)(&Ms[loff]) = pm;
  __syncthreads();
  // block's 4 chunks are contiguous in global: ((b*128+T)*2+0)*512 shorts
  const size_t gbase = ((size_t)b * 128 + T) * 2 * 512;
  ((uint4*)(Xb16 + gbase))[tid] = ((const uint4*)Xs)[tid];
  ((uint4*)(Mb16 + gbase))[tid] = ((const uint4*)Ms)[tid];
}

// K2 (round-14, VERIFIED 124.9 us — byte-identical revert): packed-frag
// GEMM + dual-row interleaved selection, 2x(8-wave, 16-row) blocks/CU.
// Round-15 lesson: 32-row/1-block-per-CU variant lost the GEMM<->select
// phase overlap between co-resident blocks (-32 us). 2 blocks/CU optimum.
__global__ __launch_bounds__(512)
__attribute__((amdgpu_waves_per_eu(4, 4)))
void rows_kernel(
    const short* __restrict__ Xb16, const short* __restrict__ Mb16,
    float* __restrict__ C) {
  __shared__ unsigned short yxu[16 * YP];   // 65,280 B
  __shared__ unsigned histS[16 * 256];      // 16 KB: 2 hists per wave
  // total 81,664 B <= 81,920 -> 2 blocks/CU preserved

  const int tid = threadIdx.x;
  const int w = tid >> 6, lane = tid & 63;
  const int nl = lane & 15, q = lane >> 4;
  const int b = blockIdx.x >> 7;            // 128 row-blocks per batch
  const int f0 = (blockIdx.x & 127) * 16;
  const int g0 = 256 * w;

  const short* __restrict__ Xb = Xb16 + (size_t)b * F_ * N_;
  const short* __restrict__ Mb = Mb16 + (size_t)b * F_ * N_;

  // A-frags: packed chunk t16 = f0>>4; s=0/1 halves adjacent (512 shorts)
  const short* Axp = Xb + (size_t)(f0 >> 4) * 1024 + lane * 8;
  const short* Amp = Mb + (size_t)(f0 >> 4) * 1024 + lane * 8;
  const bf16x8 ax0 = *(const bf16x8*)(Axp);
  const bf16x8 ax1 = *(const bf16x8*)(Axp + 512);
  const bf16x8 am0 = *(const bf16x8*)(Amp);
  const bf16x8 am1 = *(const bf16x8*)(Amp + 512);

  v4f acc[16];
#pragma unroll
  for (int t = 0; t < 16; ++t) acc[t] = (v4f)(0.f);

#pragma unroll
  for (int t = 0; t < 16; ++t) {
    // B chunk t16 = 16w + t
    const short* Bmp = Mb + (size_t)(16 * w + t) * 1024 + lane * 8;
    const short* Bxp = Xb + (size_t)(16 * w + t) * 1024 + lane * 8;
    const bf16x8 bm0 = *(const bf16x8*)(Bmp);
    const bf16x8 bm1 = *(const bf16x8*)(Bmp + 512);
    const bf16x8 bx0 = *(const bf16x8*)(Bxp);
    const bf16x8 bx1 = *(const bf16x8*)(Bxp + 512);
    acc[t] = __builtin_amdgcn_mfma_f32_16x16x32_bf16(ax0, bm0, acc[t], 0, 0, 0);
    acc[t] = __builtin_amdgcn_mfma_f32_16x16x32_bf16(ax1, bm1, acc[t], 0, 0, 0);
    acc[t] = __builtin_amdgcn_mfma_f32_16x16x32_bf16(am0, bx0, acc[t], 0, 0, 0);
    acc[t] = __builtin_amdgcn_mfma_f32_16x16x32_bf16(am1, bx1, acc[t], 0, 0, 0);
  }

  // C-frag (col=lane&15, row=q*4+r, verified m89/m91) -> LDS bf16 keys
#pragma unroll
  for (int t = 0; t < 16; ++t) {
    const int col = g0 + 16 * t + nl;
#pragma unroll
    for (int r = 0; r < 4; ++r)
      yxu[(4 * q + r) * YP + col] = (unsigned short)f2bf(acc[t][r]);
  }
  __syncthreads();

  // ---- dual-row selection: rows 2w (suffix 0) and 2w+1 (suffix 1) ----
  unsigned* wh0 = &histS[w << 9];
  unsigned* wh1 = wh0 + 256;
  const int frow0 = f0 + 2 * w, frow1 = frow0 + 1;
  const uint4* rp0 = (const uint4*)(yxu + (2 * w) * YP);
  const uint4* rp1 = (const uint4*)(yxu + (2 * w + 1) * YP);

  // pk load + ordpair + min/max, both rows interleaved
  unsigned pk0[16], pk1[16];
  unsigned kmin0 = 0xFFFFFFFFu, kmax0 = 0u, kmin1 = 0xFFFFFFFFu, kmax1 = 0u;
#pragma unroll
  for (int j = 0; j < 4; ++j) {
    const uint4 t0 = rp0[lane + 64 * j];
    const uint4 t1 = rp1[lane + 64 * j];
    const unsigned w0[4] = {t0.x, t0.y, t0.z, t0.w};
    const unsigned w1[4] = {t1.x, t1.y, t1.z, t1.w};
#pragma unroll
    for (int c = 0; c < 4; ++c) {
      const unsigned o0 = ordpair(w0[c]), o1 = ordpair(w1[c]);
      pk0[4 * j + c] = o0; pk1[4 * j + c] = o1;
      kmin0 = min(kmin0, min(o0 & 0xFFFFu, o0 >> 16));
      kmax0 = max(kmax0, max(o0 & 0xFFFFu, o0 >> 16));
      kmin1 = min(kmin1, min(o1 & 0xFFFFu, o1 >> 16));
      kmax1 = max(kmax1, max(o1 & 0xFFFFu, o1 >> 16));
    }
  }
#pragma unroll
  for (int off = 32; off > 0; off >>= 1) {
    kmin0 = min(kmin0, (unsigned)__shfl_down((int)kmin0, off, 64));
    kmin1 = min(kmin1, (unsigned)__shfl_down((int)kmin1, off, 64));
    kmax0 = max(kmax0, (unsigned)__shfl_down((int)kmax0, off, 64));
    kmax1 = max(kmax1, (unsigned)__shfl_down((int)kmax1, off, 64));
  }
  kmin0 = (unsigned)__shfl((int)kmin0, 0, 64);
  kmax0 = (unsigned)__shfl((int)kmax0, 0, 64);
  kmin1 = (unsigned)__shfl((int)kmin1, 0, 64);
  kmax1 = (unsigned)__shfl((int)kmax1, 0, 64);

  // radix state per row; <=2 passes, shared barriers, own histograms
  unsigned lo0 = kmin0, R0 = kmax0 - kmin0, krem0 = K_, T0 = 0, tn0 = 0;
  unsigned lo1 = kmin1, R1 = kmax1 - kmin1, krem1 = K_, T1 = 0, tn1 = 0;
  bool done0 = false, done1 = false;
  if (R0 == 0) { T0 = lo0; tn0 = krem0; done0 = true; }
  if (R1 == 0) { T1 = lo1; tn1 = krem1; done1 = true; }

#pragma unroll 1
  for (int pass = 0; pass < 2 && !(done0 && done1); ++pass) {
    int sh0 = 0, sh1 = 0;
    if (!done0) { const int p = 31 - __builtin_clz(R0); sh0 = (p > 7) ? (p - 7) : 0; }
    if (!done1) { const int p = 31 - __builtin_clz(R1); sh1 = (p > 7) ? (p - 7) : 0; }
#pragma unroll
    for (int i = 0; i < 4; ++i) { wh0[lane + 64 * i] = 0u; wh1[lane + 64 * i] = 0u; }
    __builtin_amdgcn_wave_barrier();
    if (!done0) {
#pragma unroll
      for (int c = 0; c < 16; ++c) {
        const unsigned o = pk0[c];
        const unsigned d0 = (o & 0xFFFFu) - lo0, d1 = (o >> 16) - lo0;
        if (d0 <= R0) atomicAdd(&wh0[d0 >> sh0], 1u);
        if (d1 <= R0) atomicAdd(&wh0[d1 >> sh0], 1u);
      }
    }
    if (!done1) {
#pragma unroll
      for (int c = 0; c < 16; ++c) {
        const unsigned o = pk1[c];
        const unsigned d0 = (o & 0xFFFFu) - lo1, d1 = (o >> 16) - lo1;
        if (d0 <= R1) atomicAdd(&wh1[d0 >> sh1], 1u);
        if (d1 <= R1) atomicAdd(&wh1[d1 >> sh1], 1u);
      }
    }
    __builtin_amdgcn_wave_barrier();
    // scans: two interleaved chains (wave-uniform predicates)
    unsigned h0[4], h1[4];
#pragma unroll
    for (int i = 0; i < 4; ++i) { h0[i] = wh0[4 * lane + i]; h1[i] = wh1[4 * lane + i]; }
    unsigned a3 = h0[3], a2 = h0[2] + a3, a1 = h0[1] + a2, a0 = h0[0] + a1;
    unsigned b3 = h1[3], b2 = h1[2] + b3, b1 = h1[1] + b2, b0 = h1[0] + b1;
    unsigned tot0 = a0, tot1 = b0;
#pragma unroll
    for (int off = 1; off < 64; off <<= 1) {
      const unsigned v0 = __shfl_down(tot0, off, 64);
      const unsigned v1 = __shfl_down(tot1, off, 64);
      if (lane + off < 64) { tot0 += v0; tot1 += v1; }
    }
    if (!done0) {
      const unsigned above = tot0 - a0;
      const unsigned S4[4] = {above + a0, above + a1, above + a2, above + a3};
      unsigned packed = 0; bool found = false;
#pragma unroll
      for (int i = 0; i < 4; ++i) {
        const unsigned Sip1 = S4[i] - h0[i];
        if (S4[i] >= krem0 && Sip1 < krem0) {
          packed = ((unsigned)(4 * lane + i) << 16) | Sip1; found = true;
        }
      }
      const unsigned long long bm = __ballot(found);
      const int winner = __ffsll(bm) - 1;
      packed = (unsigned)__shfl((int)packed, winner, 64);
      const unsigned D = packed >> 16;
      krem0 -= (packed & 0xFFFFu);
      if (sh0 == 0) { T0 = lo0 + D; tn0 = krem0; done0 = true; }
      else { lo0 += (D << sh0); R0 = (1u << sh0) - 1u; }
    }
    if (!done1) {
      const unsigned above = tot1 - b0;
      const unsigned S4[4] = {above + b0, above + b1, above + b2, above + b3};
      unsigned packed = 0; bool found = false;
#pragma unroll
      for (int i = 0; i < 4; ++i) {
        const unsigned Sip1 = S4[i] - h1[i];
        if (S4[i] >= krem1 && Sip1 < krem1) {
          packed = ((unsigned)(4 * lane + i) << 16) | Sip1; found = true;
        }
      }
      const unsigned long long bm = __ballot(found);
      const int winner = __ffsll(bm) - 1;
      packed = (unsigned)__shfl((int)packed, winner, 64);
      const unsigned D = packed >> 16;
      krem1 -= (packed & 0xFFFFu);
      if (sh1 == 0) { T1 = lo1 + D; tn1 = krem1; done1 = true; }
      else { lo1 += (D << sh1); R1 = (1u << sh1) - 1u; }
    }
  }

  // final pass, both rows interleaved
  float vs0 = 0.f, ws0 = 0.f, vs1 = 0.f, ws1 = 0.f;
  unsigned cnt0[4], cnt1[4];
#pragma unroll
  for (int j = 0; j < 4; ++j) {
    cnt0[j] = 0; cnt1[j] = 0;
#pragma unroll
    for (int c = 0; c < 4; ++c) {
      const unsigned o0 = pk0[4 * j + c], o1 = pk1[4 * j + c];
      const unsigned z0[2] = {o0 & 0xFFFFu, o0 >> 16};
      const unsigned z1[2] = {o1 & 0xFFFFu, o1 >> 16};
#pragma unroll
      for (int i = 0; i < 2; ++i) {
        const int g = 512 * j + 8 * lane + 2 * c + i;
        if (z0[i] > T0) {
          const float pv = __expf(bf2f(ord2u16(z0[i])));
          vs0 += pv; ws0 += pv * fabsf((float)(g - frow0));
        } else if (z0[i] == T0) cnt0[j]++;
        if (z1[i] > T1) {
          const float pv = __expf(bf2f(ord2u16(z1[i])));
          vs1 += pv; ws1 += pv * fabsf((float)(g - frow1));
        } else if (z1[i] == T1) cnt1[j]++;
      }
    }
  }
  const float ptie0 = __expf(bf2f(ord2u16(T0)));
  const float ptie1 = __expf(bf2f(ord2u16(T1)));

  // tie scans: 4 packed prefix chains interleaved
  unsigned pA0 = cnt0[0] | (cnt0[1] << 16), pB0 = cnt0[2] | (cnt0[3] << 16);
  unsigned pA1 = cnt1[0] | (cnt1[1] << 16), pB1 = cnt1[2] | (cnt1[3] << 16);
  unsigned iA0 = pA0, iB0 = pB0, iA1 = pA1, iB1 = pB1;
#pragma unroll
  for (int off = 1; off < 64; off <<= 1) {
    const unsigned vA0 = __shfl_up(iA0, off, 64);
    const unsigned vB0 = __shfl_up(iB0, off, 64);
    const unsigned vA1 = __shfl_up(iA1, off, 64);
    const unsigned vB1 = __shfl_up(iB1, off, 64);
    if (lane >= off) { iA0 += vA0; iB0 += vB0; iA1 += vA1; iB1 += vB1; }
  }
  const unsigned eA0 = iA0 - pA0, eB0 = iB0 - pB0;
  const unsigned eA1 = iA1 - pA1, eB1 = iB1 - pB1;
  const unsigned tA0 = (unsigned)__shfl((int)iA0, 63, 64);
  const unsigned tB0 = (unsigned)__shfl((int)iB0, 63, 64);
  const unsigned tA1 = (unsigned)__shfl((int)iA1, 63, 64);
  const unsigned tB1 = (unsigned)__shfl((int)iB1, 63, 64);
  unsigned G0[4], G1[4];
  G0[0] = 0; G0[1] = tA0 & 0xFFFFu; G0[2] = G0[1] + (tA0 >> 16);
  G0[3] = G0[2] + (tB0 & 0xFFFFu);
  G1[0] = 0; G1[1] = tA1 & 0xFFFFu; G1[2] = G1[1] + (tA1 >> 16);
  G1[3] = G1[2] + (tB1 & 0xFFFFu);
#pragma unroll
  for (int j = 0; j < 4; ++j) {
    if (cnt0[j]) {
      const unsigned off = (j < 2) ? ((eA0 >> (16 * j)) & 0xFFFFu)
                                   : ((eB0 >> (16 * (j - 2))) & 0xFFFFu);
      unsigned cc = 0;
#pragma unroll
      for (int c = 0; c < 4; ++c) {
        const unsigned o = pk0[4 * j + c];
        const unsigned z[2] = {o & 0xFFFFu, o >> 16};
#pragma unroll
        for (int i = 0; i < 2; ++i) {
          if (z[i] == T0) {
            if (G0[j] + off + cc < tn0) {
              const int g = 512 * j + 8 * lane + 2 * c + i;
              vs0 += ptie0; ws0 += ptie0 * fabsf((float)(g - frow0));
            }
            cc++;
          }
        }
      }
    }
    if (cnt1[j]) {
      const unsigned off = (j < 2) ? ((eA1 >> (16 * j)) & 0xFFFFu)
                                   : ((eB1 >> (16 * (j - 2))) & 0xFFFFu);
      unsigned cc = 0;
#pragma unroll
      for (int c = 0; c < 4; ++c) {
        const unsigned o = pk1[4 * j + c];
        const unsigned z[2] = {o & 0xFFFFu, o >> 16};
#pragma unroll
        for (int i = 0; i < 2; ++i) {
          if (z[i] == T1) {
            if (G1[j] + off + cc < tn1) {
              const int g = 512 * j + 8 * lane + 2 * c + i;
              vs1 += ptie1; ws1 += ptie1 * fabsf((float)(g - frow1));
            }
            cc++;
          }
        }
      }
    }
  }

  // 4 interleaved wave reductions
#pragma unroll
  for (int off = 32; off > 0; off >>= 1) {
    vs0 += __shfl_down(vs0, off, 64);
    ws0 += __shfl_down(ws0, off, 64);
    vs1 += __shfl_down(vs1, off, 64);
    ws1 += __shfl_down(ws1, off, 64);
  }
  if (lane == 0) {
    C[(size_t)b * F_ + frow0] = (ws0 / vs0) * (1.f / (float)K_);
    C[(size_t)b * F_ + frow1] = (ws1 / vs1) * (1.f / (float)K_);
  }
}

// K3: cmin = min(C); out = mean(exp(-C + cmin - 1e-6)) (unchanged).
__global__ __launch_bounds__(1024) void final_kernel(
    const float* __restrict__ C, unsigned* __restrict__ out) {
  __shared__ float red[16];
  const int tid = threadIdx.x;
  const int wave = tid >> 6, lane = tid & 63;
  float v[32];
  float mn = 3.4e38f;
#pragma unroll
  for (int i = 0; i < 32; ++i) {
    v[i] = C[tid + 1024 * i];
    mn = fminf(mn, v[i]);
  }
  mn = -wave_max(-mn);
  if (lane == 0) red[wave] = mn;
  __syncthreads();
  float cmin = red[0];
  for (int w = 1; w < 16; ++w) cmin = fminf(cmin, red[w]);
  __syncthreads();
  float s = 0.f;
#pragma unroll
  for (int i = 0; i < 32; ++i) s += expf(cmin - v[i] - 1e-6f);
  s = wave_sum(s);
  if (lane == 0) red[wave] = s;
  __syncthreads();
  if (tid == 0) {
    float tot = 0.f;
    for (int w = 0; w < 16; ++w) tot += red[w];
    const float res = tot * (1.f / 32768.f);
    const __hip_bfloat16 hb = __float2bfloat16(res);
    const unsigned short u = *(const unsigned short*)&hb;
    out[0] = ((unsigned)u << 16) | (unsigned)u;
  }
}

extern "C" void kernel_launch(void* const* d_in, const int* in_sizes, int n_in,
                              void* d_out, int out_size, void* d_ws, size_t ws_size,
                              hipStream_t stream) {
  const float* X = (const float*)d_in[0];
  const float* M = (const float*)d_in[1];
  short* Xb16 = (short*)d_ws;                          // 4 MB (packed frags)
  short* Mb16 = Xb16 + (size_t)B_ * F_ * N_;           // 4 MB
  float* C = (float*)(Mb16 + (size_t)B_ * F_ * N_);    // 128 KB
  float* P = C + (size_t)B_ * F_;                      // 1 MB fb-major partials
  float* S = P + (size_t)64 * 4096;                    // 16 KB reduced stats

  stats_kernel<<<dim3(B_ * 64), dim3(256), 0, stream>>>(X, M, P);
  reduce_kernel<<<dim3(16), dim3(256), 0, stream>>>(P, S);
  normbf_kernel<<<dim3(B_ * 64), dim3(256), 0, stream>>>(X, M, S, Xb16, Mb16);
  rows_kernel<<<dim3(B_ * (F_ / 16)), dim3(512), 0, stream>>>(Xb16, Mb16, C);
  final_kernel<<<dim3(1), dim3(1024), 0, stream>>>(C, (unsigned*)d_out);
}

// Round 18
// 190.362 us; speedup vs baseline: 1.1819x; 1.0216x over previous
//
#include <hip/hip_runtime.h>
#include <hip/hip_bf16.h>
#include <math.h>

// Problem constants (fixed shapes from setup_inputs)
#define B_   16
#define F_   2048
#define N_   64
#define K_   1024   // F/2
#define YP   2040   // padded LDS row stride (ushorts); 16B-aligned rows

typedef short bf16x8 __attribute__((ext_vector_type(8)));  // 8 bf16 = 4 VGPR
typedef float v4f    __attribute__((ext_vector_type(4)));  // MFMA C/D frag

__device__ __forceinline__ float wave_sum(float v) {
#pragma unroll
  for (int off = 32; off > 0; off >>= 1) v += __shfl_down(v, off, 64);
  return v;
}
__device__ __forceinline__ float wave_max(float v) {
#pragma unroll
  for (int off = 32; off > 0; off >>= 1) v = fmaxf(v, __shfl_down(v, off, 64));
  return v;
}

// fp32 -> bf16 bits, round-to-nearest-even (finite inputs only)
__device__ __forceinline__ unsigned f2bf(float x) {
  const unsigned u = __float_as_uint(x);
  return (u + 0x7FFFu + ((u >> 16) & 1u)) >> 16;
}
__device__ __forceinline__ float bf2f(unsigned us) {
  return __uint_as_float(us << 16);
}
// 16-bit total-order inverse: ord -> bf16 bits
__device__ __forceinline__ unsigned ord2u16(unsigned T) {
  return (T & 0x8000u) ? (T ^ 0x8000u) : (T ^ 0xFFFFu);
}
// packed pair of ord16 keys from a dword of 2 bf16 values
__device__ __forceinline__ unsigned ordpair(unsigned wd) {
  return wd ^ (0x80008000u | (((wd & 0x80008000u) >> 15) * 0x7FFFu));
}

// K0 (round-8, verified): wide grid, fb-MAJOR P layout, atomic-free.
__global__ __launch_bounds__(256) void stats_kernel(
    const float* __restrict__ X, const float* __restrict__ M,
    float* __restrict__ P) {
  __shared__ float red[4][N_][4];   // [fi][n][word], 4 KB
  const int tid = threadIdx.x;
  const int b = blockIdx.x >> 6;
  const int fb = blockIdx.x & 63;
  const int f0 = fb * 32;
  const int fi = tid >> 6, n = tid & 63;
  float sx = 0.f, sxx = 0.f, sm = 0.f, smm = 0.f;
#pragma unroll
  for (int j = 0; j < 8; ++j) {
    const int f = f0 + fi + 4 * j;
    const size_t gi = ((size_t)b * F_ + f) * N_ + n;
    const float x = X[gi];
    const float m = M[gi];
    sx += x; sxx += x * x; sm += m; smm += m * m;
  }
  red[fi][n][0] = sx; red[fi][n][1] = sxx;
  red[fi][n][2] = sm; red[fi][n][3] = smm;
  __syncthreads();
  const int wn = tid & 63, word = tid >> 6;
  const float s = red[0][wn][word] + red[1][wn][word] +
                  red[2][wn][word] + red[3][wn][word];
  P[(size_t)fb * 4096 + b * 256 + wn * 4 + word] = s;
}

// K1 (round-18): LDS-staged normbf (round-17 verified) + FUSED fb-reduce:
// thread i sums P[fb][b*256+i] over 64 fb (coalesced, L2-hot 1MB, exact
// same summation order as the deleted reduce_kernel -> bit-identical),
// 64KB per block. Removes one kernel launch + sync gap from the pipeline.
__global__ __launch_bounds__(256) void normbf_kernel(
    const float* __restrict__ X, const float* __restrict__ M,
    const float* __restrict__ P,
    short* __restrict__ Xb16, short* __restrict__ Mb16) {
  __shared__ float sums[256];             // raw (n,word) sums, 1 KB
  __shared__ float4 Pl[64];               // (mux, rx, mum, rm) per n, 1 KB
  __shared__ unsigned short Xs[2048];     // 4 KB packed X (4 chunks)
  __shared__ unsigned short Ms[2048];     // 4 KB packed M
  const int tid = threadIdx.x;
  const int b = blockIdx.x >> 6;
  const int f0 = (blockIdx.x & 63) * 32;
  const int T = f0 >> 4;                  // first t16 chunk of this block
  {  // fused reduce (replaces reduce_kernel; identical order)
    const int i = b * 256 + tid;
    float s0 = 0.f, s1 = 0.f, s2 = 0.f, s3 = 0.f;
#pragma unroll
    for (int fb = 0; fb < 64; fb += 4) {
      s0 += P[(size_t)fb * 4096 + i];
      s1 += P[(size_t)(fb + 1) * 4096 + i];
      s2 += P[(size_t)(fb + 2) * 4096 + i];
      s3 += P[(size_t)(fb + 3) * 4096 + i];
    }
    sums[tid] = (s0 + s1) + (s2 + s3);
  }
  __syncthreads();
  if (tid < 64) {
    const float sx = sums[tid * 4 + 0], sxx = sums[tid * 4 + 1];
    const float sm = sums[tid * 4 + 2], smm = sums[tid * 4 + 3];
    const float mux = sx * (1.f / F_);
    const float mum = sm * (1.f / F_);
    const float rx =
        1.f / (sqrtf(fmaxf(sxx - (float)F_ * mux * mux, 0.f)) + 1e-10f);
    const float rm =
        1.f / (sqrtf(fmaxf(smm - (float)F_ * mum * mum, 0.f)) + 1e-10f);
    Pl[tid] = make_float4(mux, rx, mum, rm);
  }
  __syncthreads();
  const int t16l = tid >> 7, r = tid & 127;
  const int nl = r >> 3, sq = r & 7;      // sq = s_*4 + q_
  const int f = (T + t16l) * 16 + nl;
  const int n0 = 8 * sq;                  // = 32*s_ + 8*q_
  const size_t gi = ((size_t)b * F_ + f) * N_ + n0;
  const float4 xa = *(const float4*)(X + gi);
  const float4 xb = *(const float4*)(X + gi + 4);
  const float4 ma = *(const float4*)(M + gi);
  const float4 mb = *(const float4*)(M + gi + 4);
  const float xs8[8] = {xa.x, xa.y, xa.z, xa.w, xb.x, xb.y, xb.z, xb.w};
  const float ms8[8] = {ma.x, ma.y, ma.z, ma.w, mb.x, mb.y, mb.z, mb.w};
  unsigned xv[8], mv[8];
#pragma unroll
  for (int j = 0; j < 8; ++j) {
    const float4 p = Pl[n0 + j];
    xv[j] = f2bf((xs8[j] - p.x) * p.y);
    mv[j] = f2bf((ms8[j] - p.z) * p.w);
  }
  const int s_ = sq >> 2, q_ = sq & 3;
  const int loff = (t16l * 2 + s_) * 512 + (q_ * 16 + nl) * 8;
  uint4 px, pm;
  px.x = xv[0] | (xv[1] << 16); px.y = xv[2] | (xv[3] << 16);
  px.z = xv[4] | (xv[5] << 16); px.w = xv[6] | (xv[7] << 16);
  pm.x = mv[0] | (mv[1] << 16); pm.y = mv[2] | (mv[3] << 16);
  pm.z = mv[4] | (mv[5] << 16); pm.w = mv[6] | (mv[7] << 16);
  *(uint4*)(&Xs[loff]) = px;
  *(uint4*)(&Ms[loff]) = pm;
  __syncthreads();
  // block's 4 chunks are contiguous in global: ((b*128+T)*2+0)*512 shorts
  const size_t gbase = ((size_t)b * 128 + T) * 2 * 512;
  ((uint4*)(Xb16 + gbase))[tid] = ((const uint4*)Xs)[tid];
  ((uint4*)(Mb16 + gbase))[tid] = ((const uint4*)Ms)[tid];
}

// K2 (round-18): round-14 verified kernel (124.9 us) with XCD
// BATCH-LOCALITY SWIZZLE: bid -> (b = 2*(bid&7) + (bid>>3)/128,
// f0 = ((bid>>3)%128)*16). Under the %8 XCD round-robin dispatch
// heuristic, XCD k serves only batches {2k, 2k+1} sequentially ->
// concurrent working set = one 4MB packed panel = one XCD L2
// (FETCH_SIZE showed 33MB vs 8MB ideal = 4x cross-XCD overfetch).
// Bijective: 8 x 2 x 128 = 2048. Everything else byte-identical.
__global__ __launch_bounds__(512)
__attribute__((amdgpu_waves_per_eu(4, 4)))
void rows_kernel(
    const short* __restrict__ Xb16, const short* __restrict__ Mb16,
    float* __restrict__ C) {
  __shared__ unsigned short yxu[16 * YP];   // 65,280 B
  __shared__ unsigned histS[16 * 256];      // 16 KB: 2 hists per wave
  // total 81,664 B <= 81,920 -> 2 blocks/CU preserved

  const int tid = threadIdx.x;
  const int w = tid >> 6, lane = tid & 63;
  const int nl = lane & 15, q = lane >> 4;
  const int bid = blockIdx.x;
  const int rr = bid >> 3;
  const int b = 2 * (bid & 7) + (rr >> 7);  // XCD batch-locality swizzle
  const int f0 = (rr & 127) * 16;
  const int g0 = 256 * w;

  const short* __restrict__ Xb = Xb16 + (size_t)b * F_ * N_;
  const short* __restrict__ Mb = Mb16 + (size_t)b * F_ * N_;

  // A-frags: packed chunk t16 = f0>>4; s=0/1 halves adjacent (512 shorts)
  const short* Axp = Xb + (size_t)(f0 >> 4) * 1024 + lane * 8;
  const short* Amp = Mb + (size_t)(f0 >> 4) * 1024 + lane * 8;
  const bf16x8 ax0 = *(const bf16x8*)(Axp);
  const bf16x8 ax1 = *(const bf16x8*)(Axp + 512);
  const bf16x8 am0 = *(const bf16x8*)(Amp);
  const bf16x8 am1 = *(const bf16x8*)(Amp + 512);

  v4f acc[16];
#pragma unroll
  for (int t = 0; t < 16; ++t) acc[t] = (v4f)(0.f);

#pragma unroll
  for (int t = 0; t < 16; ++t) {
    // B chunk t16 = 16w + t
    const short* Bmp = Mb + (size_t)(16 * w + t) * 1024 + lane * 8;
    const short* Bxp = Xb + (size_t)(16 * w + t) * 1024 + lane * 8;
    const bf16x8 bm0 = *(const bf16x8*)(Bmp);
    const bf16x8 bm1 = *(const bf16x8*)(Bmp + 512);
    const bf16x8 bx0 = *(const bf16x8*)(Bxp);
    const bf16x8 bx1 = *(const bf16x8*)(Bxp + 512);
    acc[t] = __builtin_amdgcn_mfma_f32_16x16x32_bf16(ax0, bm0, acc[t], 0, 0, 0);
    acc[t] = __builtin_amdgcn_mfma_f32_16x16x32_bf16(ax1, bm1, acc[t], 0, 0, 0);
    acc[t] = __builtin_amdgcn_mfma_f32_16x16x32_bf16(am0, bx0, acc[t], 0, 0, 0);
    acc[t] = __builtin_amdgcn_mfma_f32_16x16x32_bf16(am1, bx1, acc[t], 0, 0, 0);
  }

  // C-frag (col=lane&15, row=q*4+r, verified m89/m91) -> LDS bf16 keys
#pragma unroll
  for (int t = 0; t < 16; ++t) {
    const int col = g0 + 16 * t + nl;
#pragma unroll
    for (int r = 0; r < 4; ++r)
      yxu[(4 * q + r) * YP + col] = (unsigned short)f2bf(acc[t][r]);
  }
  __syncthreads();

  // ---- dual-row selection: rows 2w (suffix 0) and 2w+1 (suffix 1) ----
  unsigned* wh0 = &histS[w << 9];
  unsigned* wh1 = wh0 + 256;
  const int frow0 = f0 + 2 * w, frow1 = frow0 + 1;
  const uint4* rp0 = (const uint4*)(yxu + (2 * w) * YP);
  const uint4* rp1 = (const uint4*)(yxu + (2 * w + 1) * YP);

  // pk load + ordpair + min/max, both rows interleaved
  unsigned pk0[16], pk1[16];
  unsigned kmin0 = 0xFFFFFFFFu, kmax0 = 0u, kmin1 = 0xFFFFFFFFu, kmax1 = 0u;
#pragma unroll
  for (int j = 0; j < 4; ++j) {
    const uint4 t0 = rp0[lane + 64 * j];
    const uint4 t1 = rp1[lane + 64 * j];
    const unsigned w0[4] = {t0.x, t0.y, t0.z, t0.w};
    const unsigned w1[4] = {t1.x, t1.y, t1.z, t1.w};
#pragma unroll
    for (int c = 0; c < 4; ++c) {
      const unsigned o0 = ordpair(w0[c]), o1 = ordpair(w1[c]);
      pk0[4 * j + c] = o0; pk1[4 * j + c] = o1;
      kmin0 = min(kmin0, min(o0 & 0xFFFFu, o0 >> 16));
      kmax0 = max(kmax0, max(o0 & 0xFFFFu, o0 >> 16));
      kmin1 = min(kmin1, min(o1 & 0xFFFFu, o1 >> 16));
      kmax1 = max(kmax1, max(o1 & 0xFFFFu, o1 >> 16));
    }
  }
#pragma unroll
  for (int off = 32; off > 0; off >>= 1) {
    kmin0 = min(kmin0, (unsigned)__shfl_down((int)kmin0, off, 64));
    kmin1 = min(kmin1, (unsigned)__shfl_down((int)kmin1, off, 64));
    kmax0 = max(kmax0, (unsigned)__shfl_down((int)kmax0, off, 64));
    kmax1 = max(kmax1, (unsigned)__shfl_down((int)kmax1, off, 64));
  }
  kmin0 = (unsigned)__shfl((int)kmin0, 0, 64);
  kmax0 = (unsigned)__shfl((int)kmax0, 0, 64);
  kmin1 = (unsigned)__shfl((int)kmin1, 0, 64);
  kmax1 = (unsigned)__shfl((int)kmax1, 0, 64);

  // radix state per row; <=2 passes, shared barriers, own histograms
  unsigned lo0 = kmin0, R0 = kmax0 - kmin0, krem0 = K_, T0 = 0, tn0 = 0;
  unsigned lo1 = kmin1, R1 = kmax1 - kmin1, krem1 = K_, T1 = 0, tn1 = 0;
  bool done0 = false, done1 = false;
  if (R0 == 0) { T0 = lo0; tn0 = krem0; done0 = true; }
  if (R1 == 0) { T1 = lo1; tn1 = krem1; done1 = true; }

#pragma unroll 1
  for (int pass = 0; pass < 2 && !(done0 && done1); ++pass) {
    int sh0 = 0, sh1 = 0;
    if (!done0) { const int p = 31 - __builtin_clz(R0); sh0 = (p > 7) ? (p - 7) : 0; }
    if (!done1) { const int p = 31 - __builtin_clz(R1); sh1 = (p > 7) ? (p - 7) : 0; }
#pragma unroll
    for (int i = 0; i < 4; ++i) { wh0[lane + 64 * i] = 0u; wh1[lane + 64 * i] = 0u; }
    __builtin_amdgcn_wave_barrier();
    if (!done0) {
#pragma unroll
      for (int c = 0; c < 16; ++c) {
        const unsigned o = pk0[c];
        const unsigned d0 = (o & 0xFFFFu) - lo0, d1 = (o >> 16) - lo0;
        if (d0 <= R0) atomicAdd(&wh0[d0 >> sh0], 1u);
        if (d1 <= R0) atomicAdd(&wh0[d1 >> sh0], 1u);
      }
    }
    if (!done1) {
#pragma unroll
      for (int c = 0; c < 16; ++c) {
        const unsigned o = pk1[c];
        const unsigned d0 = (o & 0xFFFFu) - lo1, d1 = (o >> 16) - lo1;
        if (d0 <= R1) atomicAdd(&wh1[d0 >> sh1], 1u);
        if (d1 <= R1) atomicAdd(&wh1[d1 >> sh1], 1u);
      }
    }
    __builtin_amdgcn_wave_barrier();
    // scans: two interleaved chains (wave-uniform predicates)
    unsigned h0[4], h1[4];
#pragma unroll
    for (int i = 0; i < 4; ++i) { h0[i] = wh0[4 * lane + i]; h1[i] = wh1[4 * lane + i]; }
    unsigned a3 = h0[3], a2 = h0[2] + a3, a1 = h0[1] + a2, a0 = h0[0] + a1;
    unsigned b3 = h1[3], b2 = h1[2] + b3, b1 = h1[1] + b2, b0 = h1[0] + b1;
    unsigned tot0 = a0, tot1 = b0;
#pragma unroll
    for (int off = 1; off < 64; off <<= 1) {
      const unsigned v0 = __shfl_down(tot0, off, 64);
      const unsigned v1 = __shfl_down(tot1, off, 64);
      if (lane + off < 64) { tot0 += v0; tot1 += v1; }
    }
    if (!done0) {
      const unsigned above = tot0 - a0;
      const unsigned S4[4] = {above + a0, above + a1, above + a2, above + a3};
      unsigned packed = 0; bool found = false;
#pragma unroll
      for (int i = 0; i < 4; ++i) {
        const unsigned Sip1 = S4[i] - h0[i];
        if (S4[i] >= krem0 && Sip1 < krem0) {
          packed = ((unsigned)(4 * lane + i) << 16) | Sip1; found = true;
        }
      }
      const unsigned long long bm = __ballot(found);
      const int winner = __ffsll(bm) - 1;
      packed = (unsigned)__shfl((int)packed, winner, 64);
      const unsigned D = packed >> 16;
      krem0 -= (packed & 0xFFFFu);
      if (sh0 == 0) { T0 = lo0 + D; tn0 = krem0; done0 = true; }
      else { lo0 += (D << sh0); R0 = (1u << sh0) - 1u; }
    }
    if (!done1) {
      const unsigned above = tot1 - b0;
      const unsigned S4[4] = {above + b0, above + b1, above + b2, above + b3};
      unsigned packed = 0; bool found = false;
#pragma unroll
      for (int i = 0; i < 4; ++i) {
        const unsigned Sip1 = S4[i] - h1[i];
        if (S4[i] >= krem1 && Sip1 < krem1) {
          packed = ((unsigned)(4 * lane + i) << 16) | Sip1; found = true;
        }
      }
      const unsigned long long bm = __ballot(found);
      const int winner = __ffsll(bm) - 1;
      packed = (unsigned)__shfl((int)packed, winner, 64);
      const unsigned D = packed >> 16;
      krem1 -= (packed & 0xFFFFu);
      if (sh1 == 0) { T1 = lo1 + D; tn1 = krem1; done1 = true; }
      else { lo1 += (D << sh1); R1 = (1u << sh1) - 1u; }
    }
  }

  // final pass, both rows interleaved
  float vs0 = 0.f, ws0 = 0.f, vs1 = 0.f, ws1 = 0.f;
  unsigned cnt0[4], cnt1[4];
#pragma unroll
  for (int j = 0; j < 4; ++j) {
    cnt0[j] = 0; cnt1[j] = 0;
#pragma unroll
    for (int c = 0; c < 4; ++c) {
      const unsigned o0 = pk0[4 * j + c], o1 = pk1[4 * j + c];
      const unsigned z0[2] = {o0 & 0xFFFFu, o0 >> 16};
      const unsigned z1[2] = {o1 & 0xFFFFu, o1 >> 16};
#pragma unroll
      for (int i = 0; i < 2; ++i) {
        const int g = 512 * j + 8 * lane + 2 * c + i;
        if (z0[i] > T0) {
          const float pv = __expf(bf2f(ord2u16(z0[i])));
          vs0 += pv; ws0 += pv * fabsf((float)(g - frow0));
        } else if (z0[i] == T0) cnt0[j]++;
        if (z1[i] > T1) {
          const float pv = __expf(bf2f(ord2u16(z1[i])));
          vs1 += pv; ws1 += pv * fabsf((float)(g - frow1));
        } else if (z1[i] == T1) cnt1[j]++;
      }
    }
  }
  const float ptie0 = __expf(bf2f(ord2u16(T0)));
  const float ptie1 = __expf(bf2f(ord2u16(T1)));

  // tie scans: 4 packed prefix chains interleaved
  unsigned pA0 = cnt0[0] | (cnt0[1] << 16), pB0 = cnt0[2] | (cnt0[3] << 16);
  unsigned pA1 = cnt1[0] | (cnt1[1] << 16), pB1 = cnt1[2] | (cnt1[3] << 16);
  unsigned iA0 = pA0, iB0 = pB0, iA1 = pA1, iB1 = pB1;
#pragma unroll
  for (int off = 1; off < 64; off <<= 1) {
    const unsigned vA0 = __shfl_up(iA0, off, 64);
    const unsigned vB0 = __shfl_up(iB0, off, 64);
    const unsigned vA1 = __shfl_up(iA1, off, 64);
    const unsigned vB1 = __shfl_up(iB1, off, 64);
    if (lane >= off) { iA0 += vA0; iB0 += vB0; iA1 += vA1; iB1 += vB1; }
  }
  const unsigned eA0 = iA0 - pA0, eB0 = iB0 - pB0;
  const unsigned eA1 = iA1 - pA1, eB1 = iB1 - pB1;
  const unsigned tA0 = (unsigned)__shfl((int)iA0, 63, 64);
  const unsigned tB0 = (unsigned)__shfl((int)iB0, 63, 64);
  const unsigned tA1 = (unsigned)__shfl((int)iA1, 63, 64);
  const unsigned tB1 = (unsigned)__shfl((int)iB1, 63, 64);
  unsigned G0[4], G1[4];
  G0[0] = 0; G0[1] = tA0 & 0xFFFFu; G0[2] = G0[1] + (tA0 >> 16);
  G0[3] = G0[2] + (tB0 & 0xFFFFu);
  G1[0] = 0; G1[1] = tA1 & 0xFFFFu; G1[2] = G1[1] + (tA1 >> 16);
  G1[3] = G1[2] + (tB1 & 0xFFFFu);
#pragma unroll
  for (int j = 0; j < 4; ++j) {
    if (cnt0[j]) {
      const unsigned off = (j < 2) ? ((eA0 >> (16 * j)) & 0xFFFFu)
                                   : ((eB0 >> (16 * (j - 2))) & 0xFFFFu);
      unsigned cc = 0;
#pragma unroll
      for (int c = 0; c < 4; ++c) {
        const unsigned o = pk0[4 * j + c];
        const unsigned z[2] = {o & 0xFFFFu, o >> 16};
#pragma unroll
        for (int i = 0; i < 2; ++i) {
          if (z[i] == T0) {
            if (G0[j] + off + cc < tn0) {
              const int g = 512 * j + 8 * lane + 2 * c + i;
              vs0 += ptie0; ws0 += ptie0 * fabsf((float)(g - frow0));
            }
            cc++;
          }
        }
      }
    }
    if (cnt1[j]) {
      const unsigned off = (j < 2) ? ((eA1 >> (16 * j)) & 0xFFFFu)
                                   : ((eB1 >> (16 * (j - 2))) & 0xFFFFu);
      unsigned cc = 0;
#pragma unroll
      for (int c = 0; c < 4; ++c) {
        const unsigned o = pk1[4 * j + c];
        const unsigned z[2] = {o & 0xFFFFu, o >> 16};
#pragma unroll
        for (int i = 0; i < 2; ++i) {
          if (z[i] == T1) {
            if (G1[j] + off + cc < tn1) {
              const int g = 512 * j + 8 * lane + 2 * c + i;
              vs1 += ptie1; ws1 += ptie1 * fabsf((float)(g - frow1));
            }
            cc++;
          }
        }
      }
    }
  }

  // 4 interleaved wave reductions
#pragma unroll
  for (int off = 32; off > 0; off >>= 1) {
    vs0 += __shfl_down(vs0, off, 64);
    ws0 += __shfl_down(ws0, off, 64);
    vs1 += __shfl_down(vs1, off, 64);
    ws1 += __shfl_down(ws1, off, 64);
  }
  if (lane == 0) {
    C[(size_t)b * F_ + frow0] = (ws0 / vs0) * (1.f / (float)K_);
    C[(size_t)b * F_ + frow1] = (ws1 / vs1) * (1.f / (float)K_);
  }
}

// K3: cmin = min(C); out = mean(exp(-C + cmin - 1e-6)) (unchanged).
__global__ __launch_bounds__(1024) void final_kernel(
    const float* __restrict__ C, unsigned* __restrict__ out) {
  __shared__ float red[16];
  const int tid = threadIdx.x;
  const int wave = tid >> 6, lane = tid & 63;
  float v[32];
  float mn = 3.4e38f;
#pragma unroll
  for (int i = 0; i < 32; ++i) {
    v[i] = C[tid + 1024 * i];
    mn = fminf(mn, v[i]);
  }
  mn = -wave_max(-mn);
  if (lane == 0) red[wave] = mn;
  __syncthreads();
  float cmin = red[0];
  for (int w = 1; w < 16; ++w) cmin = fminf(cmin, red[w]);
  __syncthreads();
  float s = 0.f;
#pragma unroll
  for (int i = 0; i < 32; ++i) s += expf(cmin - v[i] - 1e-6f);
  s = wave_sum(s);
  if (lane == 0) red[wave] = s;
  __syncthreads();
  if (tid == 0) {
    float tot = 0.f;
    for (int w = 0; w < 16; ++w) tot += red[w];
    const float res = tot * (1.f / 32768.f);
    const __hip_bfloat16 hb = __float2bfloat16(res);
    const unsigned short u = *(const unsigned short*)&hb;
    out[0] = ((unsigned)u << 16) | (unsigned)u;
  }
}

extern "C" void kernel_launch(void* const* d_in, const int* in_sizes, int n_in,
                              void* d_out, int out_size, void* d_ws, size_t ws_size,
                              hipStream_t stream) {
  const float* X = (const float*)d_in[0];
  const float* M = (const float*)d_in[1];
  short* Xb16 = (short*)d_ws;                          // 4 MB (packed frags)
  short* Mb16 = Xb16 + (size_t)B_ * F_ * N_;           // 4 MB
  float* C = (float*)(Mb16 + (size_t)B_ * F_ * N_);    // 128 KB
  float* P = C + (size_t)B_ * F_;                      // 1 MB fb-major partials

  stats_kernel<<<dim3(B_ * 64), dim3(256), 0, stream>>>(X, M, P);
  normbf_kernel<<<dim3(B_ * 64), dim3(256), 0, stream>>>(X, M, P, Xb16, Mb16);
  rows_kernel<<<dim3(B_ * (F_ / 16)), dim3(512), 0, stream>>>(Xb16, Mb16, C);
  final_kernel<<<dim3(1), dim3(1024), 0, stream>>>(C, (unsigned*)d_out);
}